// Round 3
// baseline (4071.845 us; speedup 1.0000x reference)
//
#include <hip/hip_runtime.h>
#include <cstddef>
#include <cmath>

// ============================ CSR build ============================
__global__ void k_init_cnt(unsigned int* __restrict__ cnt, int N) {
    int i = blockIdx.x * 256 + threadIdx.x;
    if (i < N) cnt[i] = 1u;   // self-loop pre-counted
}

__global__ void k_count(const int* __restrict__ ei, int E, unsigned int* __restrict__ cnt) {
    int e = blockIdx.x * 256 + threadIdx.x;
    if (e < E) atomicAdd(&cnt[ei[E + e]], 1u);
}

// exclusive scan (single block, 1024 threads)
__global__ __launch_bounds__(1024) void k_scan(const unsigned int* __restrict__ cnt,
                                               unsigned int* __restrict__ off, int N) {
    __shared__ unsigned int sums[1024];
    int t = threadIdx.x;
    int chunk = (N + 1023) >> 10;
    int lo = t * chunk, hi = min(lo + chunk, N);
    unsigned int s = 0;
    for (int i = lo; i < hi; ++i) s += cnt[i];
    sums[t] = s;
    __syncthreads();
    for (int d = 1; d < 1024; d <<= 1) {
        unsigned int v = (t >= d) ? sums[t - d] : 0u;
        __syncthreads();
        sums[t] += v;
        __syncthreads();
    }
    unsigned int run = (t == 0) ? 0u : sums[t - 1];
    for (int i = lo; i < hi; ++i) { off[i] = run; run += cnt[i]; }
}

__global__ void k_fill(const unsigned int* __restrict__ off, unsigned int* __restrict__ cur,
                       unsigned int* __restrict__ list, int N) {
    int n = blockIdx.x * 256 + threadIdx.x;
    if (n < N) { unsigned int o = off[n]; list[o] = (unsigned int)n; cur[n] = o + 1u; }
}

__global__ void k_scatter(const int* __restrict__ ei, int E,
                          unsigned int* __restrict__ cur, unsigned int* __restrict__ list) {
    int e = blockIdx.x * 256 + threadIdx.x;
    if (e < E) {
        int d = ei[E + e];
        unsigned int p = atomicAdd(&cur[d], 1u);
        list[p] = (unsigned int)ei[e];
    }
}

// ===================== edge kernel: one wave per dst =====================
// lane = output channel. W1/W2 columns preloaded per lane (once per wave).
// Per edge: h (64 chans, lane-per-chan) computed in regs, broadcast via
// v_readlane (VALU pipe, no LDS), max-agg in a register. No atomics.
static __device__ __forceinline__ float rl(float v, int l) {
    return __int_as_float(__builtin_amdgcn_readlane(__float_as_int(v), l));
}

#define TPB_E 256
__global__ __launch_bounds__(TPB_E, 3) void edge_kernel(
    const float* __restrict__ x, const float* __restrict__ pos,
    const unsigned int* __restrict__ off, const unsigned int* __restrict__ cur,
    const unsigned int* __restrict__ list,
    const float* __restrict__ W1, const float* __restrict__ b1,
    const float* __restrict__ W2, const float* __restrict__ b2,
    float* __restrict__ agg, int N)
{
    int lane = threadIdx.x & 63;
    int dst  = blockIdx.x * 4 + (threadIdx.x >> 6);
    if (dst >= N) return;

    float w1c[6];
#pragma unroll
    for (int k = 0; k < 6; ++k) w1c[k] = W1[k * 64 + lane];
    float b1c = b1[lane], b2c = b2[lane];
    float w2c[64];
#pragma unroll
    for (int j = 0; j < 64; ++j) w2c[j] = W2[j * 64 + lane];

    unsigned int o0 = off[dst];
    int cnt = (int)(cur[dst] - o0);
    float pi0 = pos[dst * 3 + 0], pi1 = pos[dst * 3 + 1], pi2 = pos[dst * 3 + 2];

    float m = -INFINITY;
    for (int base = 0; base < cnt; base += 8) {
        int nb = min(8, cnt - base);
        // lanes 0..7 stage one edge each (x_j, pos_j - pos_i) into registers
        float in0 = 0.f, in1 = 0.f, in2 = 0.f, in3 = 0.f, in4 = 0.f, in5 = 0.f;
        if (lane < 8) {
            int i = base + lane;
            int s = (i < cnt) ? (int)list[o0 + i] : dst;
            in0 = x[s * 3 + 0]; in1 = x[s * 3 + 1]; in2 = x[s * 3 + 2];
            in3 = pos[s * 3 + 0] - pi0; in4 = pos[s * 3 + 1] - pi1; in5 = pos[s * 3 + 2] - pi2;
        }
        // phase A: h[e] = relu(layer1) for my channel (=lane), all 8 edges
        float h[8];
#pragma unroll
        for (int e = 0; e < 8; ++e) {
            float t = b1c;
            t = fmaf(rl(in0, e), w1c[0], t);
            t = fmaf(rl(in1, e), w1c[1], t);
            t = fmaf(rl(in2, e), w1c[2], t);
            t = fmaf(rl(in3, e), w1c[3], t);
            t = fmaf(rl(in4, e), w1c[4], t);
            t = fmaf(rl(in5, e), w1c[5], t);
            h[e] = fmaxf(t, 0.f);
        }
        // phase B: layer2 for my channel, readlane-broadcast h, 4 acc chains
#pragma unroll
        for (int e = 0; e < 8; ++e) {
            if (e >= nb) break;
            int hh = __float_as_int(h[e]);
            float t0 = b2c, t1 = 0.f, t2 = 0.f, t3 = 0.f;
#pragma unroll
            for (int j = 0; j < 64; j += 4) {
                t0 = fmaf(__int_as_float(__builtin_amdgcn_readlane(hh, j + 0)), w2c[j + 0], t0);
                t1 = fmaf(__int_as_float(__builtin_amdgcn_readlane(hh, j + 1)), w2c[j + 1], t1);
                t2 = fmaf(__int_as_float(__builtin_amdgcn_readlane(hh, j + 2)), w2c[j + 2], t2);
                t3 = fmaf(__int_as_float(__builtin_amdgcn_readlane(hh, j + 3)), w2c[j + 3], t3);
            }
            m = fmaxf(m, (t0 + t1) + (t2 + t3));
        }
    }
    agg[(size_t)dst * 64 + lane] = m;
}

// ===================== node kernel: 64 nodes x 2 K-splits per block =====================
// split s handles g2 channels [s*512, s*512+512). g1 exchanged via LDS then held
// in registers (g1r[128]+g3p[64] ~ 205 VGPR; launch_bounds(128,2) -> 256 cap).
#define TPB_N 128
__global__ __launch_bounds__(TPB_N, 2) void node_kernel(
    const float* __restrict__ agg,
    const float* __restrict__ W3, const float* __restrict__ b3,
    const float* __restrict__ W4, const float* __restrict__ b4,
    const float* __restrict__ W5, const float* __restrict__ b5,
    const float* __restrict__ Wf, const float* __restrict__ bf,
    float* __restrict__ out, int N)
{
    __shared__ float g1s[64][129];  // stride 129: bank=(lane+j)%32, 2-way free
    __shared__ float g3s[64][65];
    int lane = threadIdx.x & 63, s = threadIdx.x >> 6;
    int node = blockIdx.x * 64 + lane;
    bool valid = node < N;

    // ---- phase 1: split s computes g1 channels [s*64, s*64+64) ----
    float av[64];
    {
        const float* arow = agg + (size_t)(valid ? node : 0) * 64;
#pragma unroll
        for (int j = 0; j < 64; j += 4) {
            float4 v = *(const float4*)(arow + j);
            av[j] = v.x; av[j + 1] = v.y; av[j + 2] = v.z; av[j + 3] = v.w;
        }
    }
#pragma unroll
    for (int ch = 0; ch < 2; ++ch) {
        int cbase = s * 64 + ch * 32;
        float acc[32];
#pragma unroll
        for (int q = 0; q < 32; ++q) acc[q] = b3[cbase + q];
#pragma unroll 4
        for (int j = 0; j < 64; ++j) {
            float aj = av[j];
            const float* w = W3 + j * 128 + cbase;
#pragma unroll
            for (int q = 0; q < 32; ++q) acc[q] = fmaf(aj, w[q], acc[q]);
        }
#pragma unroll
        for (int q = 0; q < 32; ++q) g1s[lane][cbase + q] = fmaxf(acc[q], 0.f);
    }
    __syncthreads();

    // ---- read full g1 into registers ----
    float g1r[128];
#pragma unroll
    for (int j = 0; j < 128; ++j) g1r[j] = g1s[lane][j];

    // ---- phase 2: my 512 g2 channels -> partial g3 ----
    float g3p[64];
#pragma unroll
    for (int c = 0; c < 64; ++c) g3p[c] = (s == 0) ? b5[c] : 0.f;

    int kc0 = s * 64;
    for (int kc = kc0; kc < kc0 + 64; ++kc) {   // 64 chunks x 8 g2-channels
        float t[8];
#pragma unroll
        for (int q = 0; q < 8; ++q) t[q] = b4[kc * 8 + q];
#pragma unroll
        for (int j = 0; j < 128; ++j) {
            float gj = g1r[j];
            const float* w = W4 + j * 1024 + kc * 8;
#pragma unroll
            for (int q = 0; q < 8; ++q) t[q] = fmaf(gj, w[q], t[q]);
        }
#pragma unroll
        for (int q = 0; q < 8; ++q) {
            float g2 = fmaxf(t[q], 0.f);
            const float* w5 = W5 + (kc * 8 + q) * 64;
#pragma unroll
            for (int c = 0; c < 64; ++c) g3p[c] = fmaf(g2, w5[c], g3p[c]);
        }
    }
    __syncthreads();
    if (s == 1) {
#pragma unroll
        for (int c = 0; c < 64; ++c) g3s[lane][c] = g3p[c];
    }
    __syncthreads();
    if (s == 0 && valid) {
        float r[64];
#pragma unroll
        for (int c = 0; c < 64; ++c) r[c] = fmaxf(g3p[c] + g3s[lane][c], 0.f);
        float o[40];
#pragma unroll
        for (int c = 0; c < 40; ++c) o[c] = bf[c];
#pragma unroll 4
        for (int j = 0; j < 64; ++j) {
            float aj = r[j];
            const float* w = Wf + j * 40;
#pragma unroll
            for (int c = 0; c < 40; ++c) o[c] = fmaf(aj, w[c], o[c]);
        }
        float mx = o[0];
#pragma unroll
        for (int c = 1; c < 40; ++c) mx = fmaxf(mx, o[c]);
        float sum = 0.f;
#pragma unroll
        for (int c = 0; c < 40; ++c) sum += expf(o[c] - mx);
        float ls = logf(sum) + mx;
        float* op = out + (size_t)node * 40;
#pragma unroll
        for (int c = 0; c < 40; ++c) op[c] = o[c] - ls;
    }
}

// ============================ launch ============================
extern "C" void kernel_launch(void* const* d_in, const int* in_sizes, int n_in,
                              void* d_out, int out_size, void* d_ws, size_t ws_size,
                              hipStream_t stream) {
    const float* x   = (const float*)d_in[0];
    const float* pos = (const float*)d_in[1];
    const int*   ei  = (const int*)d_in[2];
    const float* W1  = (const float*)d_in[3];
    const float* b1  = (const float*)d_in[4];
    const float* W2  = (const float*)d_in[5];
    const float* b2  = (const float*)d_in[6];
    const float* W3  = (const float*)d_in[7];
    const float* b3  = (const float*)d_in[8];
    const float* W4  = (const float*)d_in[9];
    const float* b4  = (const float*)d_in[10];
    const float* W5  = (const float*)d_in[11];
    const float* b5  = (const float*)d_in[12];
    const float* Wf  = (const float*)d_in[13];
    const float* bf  = (const float*)d_in[14];
    float* out = (float*)d_out;

    int Nn = in_sizes[0] / 3;   // 50000
    int E  = in_sizes[2] / 2;   // 1600000

    // workspace layout (256B aligned)
    char* w = (char*)d_ws;
    size_t p = 0;
    auto take = [&](size_t bytes) { size_t q = p; p = (p + bytes + 255) & ~size_t(255); return (void*)(w + q); };
    unsigned int* off  = (unsigned int*)take((size_t)Nn * 4);
    unsigned int* cnt  = (unsigned int*)take((size_t)Nn * 4);          // reused as cursor
    unsigned int* list = (unsigned int*)take((size_t)(E + Nn) * 4);
    float*        agg  = (float*)take((size_t)Nn * 64 * 4);

    k_init_cnt<<<(Nn + 255) / 256, 256, 0, stream>>>(cnt, Nn);
    k_count<<<(E + 255) / 256, 256, 0, stream>>>(ei, E, cnt);
    k_scan<<<1, 1024, 0, stream>>>(cnt, off, Nn);
    k_fill<<<(Nn + 255) / 256, 256, 0, stream>>>(off, cnt, list, Nn);
    k_scatter<<<(E + 255) / 256, 256, 0, stream>>>(ei, E, cnt, list);

    edge_kernel<<<(Nn + 3) / 4, TPB_E, 0, stream>>>(
        x, pos, off, cnt, list, W1, b1, W2, b2, agg, Nn);

    node_kernel<<<(Nn + 63) / 64, TPB_N, 0, stream>>>(
        agg, W3, b3, W4, b4, W5, b5, Wf, bf, out, Nn);
}

// Round 4
// 2817.914 us; speedup vs baseline: 1.4450x; 1.4450x over previous
//
#include <hip/hip_runtime.h>
#include <cstddef>
#include <cmath>

// ============================ CSR build ============================
__global__ void k_init_cnt(unsigned int* __restrict__ cnt, int N) {
    int i = blockIdx.x * 256 + threadIdx.x;
    if (i < N) cnt[i] = 1u;   // self-loop pre-counted
}

__global__ void k_count(const int* __restrict__ ei, int E, unsigned int* __restrict__ cnt) {
    int e = blockIdx.x * 256 + threadIdx.x;
    if (e < E) atomicAdd(&cnt[ei[E + e]], 1u);
}

__global__ __launch_bounds__(1024) void k_scan(const unsigned int* __restrict__ cnt,
                                               unsigned int* __restrict__ off, int N) {
    __shared__ unsigned int sums[1024];
    int t = threadIdx.x;
    int chunk = (N + 1023) >> 10;
    int lo = t * chunk, hi = min(lo + chunk, N);
    unsigned int s = 0;
    for (int i = lo; i < hi; ++i) s += cnt[i];
    sums[t] = s;
    __syncthreads();
    for (int d = 1; d < 1024; d <<= 1) {
        unsigned int v = (t >= d) ? sums[t - d] : 0u;
        __syncthreads();
        sums[t] += v;
        __syncthreads();
    }
    unsigned int run = (t == 0) ? 0u : sums[t - 1];
    for (int i = lo; i < hi; ++i) { off[i] = run; run += cnt[i]; }
}

__global__ void k_fill(const unsigned int* __restrict__ off, unsigned int* __restrict__ cur,
                       unsigned int* __restrict__ list, int N) {
    int n = blockIdx.x * 256 + threadIdx.x;
    if (n < N) { unsigned int o = off[n]; list[o] = (unsigned int)n; cur[n] = o + 1u; }
}

__global__ void k_scatter(const int* __restrict__ ei, int E,
                          unsigned int* __restrict__ cur, unsigned int* __restrict__ list) {
    int e = blockIdx.x * 256 + threadIdx.x;
    if (e < E) {
        int d = ei[E + e];
        unsigned int p = atomicAdd(&cur[d], 1u);
        list[p] = (unsigned int)ei[e];
    }
}

// ===================== edge kernel: one wave per dst (xN via stride) =====================
static __device__ __forceinline__ float rl(float v, int l) {
    return __int_as_float(__builtin_amdgcn_readlane(__float_as_int(v), l));
}

#define TPB_E 256
#define EDGE_WPB 4
__global__ __launch_bounds__(TPB_E, 3) void edge_kernel(
    const float* __restrict__ x, const float* __restrict__ pos,
    const unsigned int* __restrict__ off, const unsigned int* __restrict__ cur,
    const unsigned int* __restrict__ list,
    const float* __restrict__ W1, const float* __restrict__ b1,
    const float* __restrict__ W2, const float* __restrict__ b2,
    float* __restrict__ agg, int N, int dstStride)
{
    int lane = threadIdx.x & 63;
    int dst0 = blockIdx.x * EDGE_WPB + (threadIdx.x >> 6);

    // per-lane weight columns, pinned into VGPRs (R3: compiler rematerialized
    // these -> VGPR_Count=52; asm "+v" makes them opaque and register-resident)
    float w1c[6];
#pragma unroll
    for (int k = 0; k < 6; ++k) w1c[k] = W1[k * 64 + lane];
    float b1c = b1[lane], b2c = b2[lane];
    float w2c[64];
#pragma unroll
    for (int j = 0; j < 64; ++j) w2c[j] = W2[j * 64 + lane];
#pragma unroll
    for (int k = 0; k < 6; ++k) asm volatile("" : "+v"(w1c[k]));
#pragma unroll
    for (int j = 0; j < 64; ++j) asm volatile("" : "+v"(w2c[j]));

    for (int dst = dst0; dst < N; dst += dstStride) {
        unsigned int o0 = off[dst];
        int cnt = (int)(cur[dst] - o0);
        float pi0 = pos[dst * 3 + 0], pi1 = pos[dst * 3 + 1], pi2 = pos[dst * 3 + 2];
        float m = -INFINITY;

        // preload batch 0 (lanes 0..7 stage one edge each)
        float in0 = 0.f, in1 = 0.f, in2 = 0.f, in3 = 0.f, in4 = 0.f, in5 = 0.f;
        if (lane < 8) {
            int i = lane;
            int s = (i < cnt) ? (int)list[o0 + i] : dst;
            in0 = x[s * 3 + 0]; in1 = x[s * 3 + 1]; in2 = x[s * 3 + 2];
            in3 = pos[s * 3 + 0] - pi0; in4 = pos[s * 3 + 1] - pi1; in5 = pos[s * 3 + 2] - pi2;
        }

        for (int base = 0; base < cnt; base += 8) {
            int nb = min(8, cnt - base);
            // software-pipeline: issue next batch's gathers before computing
            float n0 = 0.f, n1 = 0.f, n2 = 0.f, n3 = 0.f, n4 = 0.f, n5 = 0.f;
            if (lane < 8 && base + 8 < cnt) {
                int i = base + 8 + lane;
                int s = (i < cnt) ? (int)list[o0 + i] : dst;
                n0 = x[s * 3 + 0]; n1 = x[s * 3 + 1]; n2 = x[s * 3 + 2];
                n3 = pos[s * 3 + 0] - pi0; n4 = pos[s * 3 + 1] - pi1; n5 = pos[s * 3 + 2] - pi2;
            }
            // phase A: h[e] = relu(layer1) for my channel (=lane)
            float h[8];
#pragma unroll
            for (int e = 0; e < 8; ++e) {
                float t = b1c;
                t = fmaf(rl(in0, e), w1c[0], t);
                t = fmaf(rl(in1, e), w1c[1], t);
                t = fmaf(rl(in2, e), w1c[2], t);
                t = fmaf(rl(in3, e), w1c[3], t);
                t = fmaf(rl(in4, e), w1c[4], t);
                t = fmaf(rl(in5, e), w1c[5], t);
                h[e] = fmaxf(t, 0.f);
            }
            // phase B: layer2 for my channel via readlane broadcast of h
#pragma unroll
            for (int e = 0; e < 8; ++e) {
                if (e >= nb) break;
                int hh = __float_as_int(h[e]);
                float t0 = b2c, t1 = 0.f, t2 = 0.f, t3 = 0.f;
#pragma unroll
                for (int j = 0; j < 64; j += 4) {
                    t0 = fmaf(__int_as_float(__builtin_amdgcn_readlane(hh, j + 0)), w2c[j + 0], t0);
                    t1 = fmaf(__int_as_float(__builtin_amdgcn_readlane(hh, j + 1)), w2c[j + 1], t1);
                    t2 = fmaf(__int_as_float(__builtin_amdgcn_readlane(hh, j + 2)), w2c[j + 2], t2);
                    t3 = fmaf(__int_as_float(__builtin_amdgcn_readlane(hh, j + 3)), w2c[j + 3], t3);
                }
                m = fmaxf(m, (t0 + t1) + (t2 + t3));
            }
            in0 = n0; in1 = n1; in2 = n2; in3 = n3; in4 = n4; in5 = n5;
        }
        agg[(size_t)dst * 64 + lane] = m;
    }
}

// ===================== node kernel: 16 nodes x 16 K-splits per 256-thread block =====================
// node = tid&15 (lane-minor => weight loads broadcast across 16 lanes, VMEM vector path),
// split = tid>>4 handles g2 channels [split*64, +64). Live set ~95 regs -> no spill at 128 cap.
#define NPB 16
__global__ __launch_bounds__(256, 4) void node_kernel(
    const float* __restrict__ agg,
    const float* __restrict__ W3, const float* __restrict__ b3,
    const float* __restrict__ W4, const float* __restrict__ b4,
    const float* __restrict__ W5, const float* __restrict__ b5,
    const float* __restrict__ Wf, const float* __restrict__ bf,
    float* __restrict__ out, int N)
{
    __shared__ float aggs[NPB][68];     // stride 68: 16B-aligned rows, 2-way banks
    __shared__ float g1s[NPB][132];     // stride 132: 16B-aligned
    __shared__ float red[4][NPB][68];   // per-wave g3 partials
    __shared__ float g3f[NPB][68];      // relu(g3)
    __shared__ float os[NPB][41];       // fc outputs

    int tid = threadIdx.x;
    int node = tid & 15;
    int split = tid >> 4;
    int n0 = blockIdx.x * NPB;

    // ---- stage agg tile (coalesced, clamped) ----
    {
        int ln = tid >> 4;
        int j4 = (tid & 15) * 4;
        int src = min(n0 + ln, N - 1);
        float4 v = *(const float4*)(agg + (size_t)src * 64 + j4);
        *(float4*)&aggs[ln][j4] = v;
    }
    __syncthreads();

    // ---- phase 1: g1 channels [split*8, +8) for my node ----
    {
        float acc[8];
        float4 bA = *(const float4*)(b3 + split * 8);
        float4 bB = *(const float4*)(b3 + split * 8 + 4);
        acc[0] = bA.x; acc[1] = bA.y; acc[2] = bA.z; acc[3] = bA.w;
        acc[4] = bB.x; acc[5] = bB.y; acc[6] = bB.z; acc[7] = bB.w;
#pragma unroll 2
        for (int j = 0; j < 64; ++j) {
            float a = aggs[node][j];
            const float* w = W3 + j * 128 + split * 8;
            float4 wA = *(const float4*)(w);
            float4 wB = *(const float4*)(w + 4);
            acc[0] = fmaf(a, wA.x, acc[0]); acc[1] = fmaf(a, wA.y, acc[1]);
            acc[2] = fmaf(a, wA.z, acc[2]); acc[3] = fmaf(a, wA.w, acc[3]);
            acc[4] = fmaf(a, wB.x, acc[4]); acc[5] = fmaf(a, wB.y, acc[5]);
            acc[6] = fmaf(a, wB.z, acc[6]); acc[7] = fmaf(a, wB.w, acc[7]);
        }
        *(float4*)&g1s[node][split * 8] =
            make_float4(fmaxf(acc[0], 0.f), fmaxf(acc[1], 0.f), fmaxf(acc[2], 0.f), fmaxf(acc[3], 0.f));
        *(float4*)&g1s[node][split * 8 + 4] =
            make_float4(fmaxf(acc[4], 0.f), fmaxf(acc[5], 0.f), fmaxf(acc[6], 0.f), fmaxf(acc[7], 0.f));
    }
    __syncthreads();

    // ---- phase 2: my 64 g2 channels -> partial g3[64] ----
    float g3p[64];
#pragma unroll
    for (int c = 0; c < 64; ++c) g3p[c] = 0.f;

    const int kc0 = split * 64;
#pragma unroll 1
    for (int chunk = 0; chunk < 8; ++chunk) {
        int kc = kc0 + chunk * 8;
        float t[8];
        {
            float4 bA = *(const float4*)(b4 + kc);
            float4 bB = *(const float4*)(b4 + kc + 4);
            t[0] = bA.x; t[1] = bA.y; t[2] = bA.z; t[3] = bA.w;
            t[4] = bB.x; t[5] = bB.y; t[6] = bB.z; t[7] = bB.w;
        }
        for (int j = 0; j < 128; j += 4) {
            float4 g = *(const float4*)&g1s[node][j];
            const float* w = W4 + (size_t)j * 1024 + kc;
#pragma unroll
            for (int jj = 0; jj < 4; ++jj) {
                float gj = (jj == 0) ? g.x : (jj == 1) ? g.y : (jj == 2) ? g.z : g.w;
                float4 wA = *(const float4*)(w + (size_t)jj * 1024);
                float4 wB = *(const float4*)(w + (size_t)jj * 1024 + 4);
                t[0] = fmaf(gj, wA.x, t[0]); t[1] = fmaf(gj, wA.y, t[1]);
                t[2] = fmaf(gj, wA.z, t[2]); t[3] = fmaf(gj, wA.w, t[3]);
                t[4] = fmaf(gj, wB.x, t[4]); t[5] = fmaf(gj, wB.y, t[5]);
                t[6] = fmaf(gj, wB.z, t[6]); t[7] = fmaf(gj, wB.w, t[7]);
            }
        }
#pragma unroll
        for (int q = 0; q < 8; ++q) {
            float g2 = fmaxf(t[q], 0.f);
            const float* w5 = W5 + (size_t)(kc + q) * 64;
#pragma unroll
            for (int c = 0; c < 64; c += 4) {
                float4 wv = *(const float4*)(w5 + c);
                g3p[c + 0] = fmaf(g2, wv.x, g3p[c + 0]);
                g3p[c + 1] = fmaf(g2, wv.y, g3p[c + 1]);
                g3p[c + 2] = fmaf(g2, wv.z, g3p[c + 2]);
                g3p[c + 3] = fmaf(g2, wv.w, g3p[c + 3]);
            }
        }
    }

    // ---- reduce 4 splits within wave (lane bits 4,5), then across waves via LDS ----
#pragma unroll
    for (int c = 0; c < 64; ++c) {
        g3p[c] += __shfl_xor(g3p[c], 16, 64);
        g3p[c] += __shfl_xor(g3p[c], 32, 64);
    }
    int wave = tid >> 6;
    if ((tid & 63) < 16) {
#pragma unroll
        for (int c = 0; c < 64; c += 4)
            *(float4*)&red[wave][node][c] = make_float4(g3p[c], g3p[c + 1], g3p[c + 2], g3p[c + 3]);
    }
    __syncthreads();
    {
        int ln = tid & 15;
        int c = (tid >> 4) * 4;
        float4 s0 = *(const float4*)&red[0][ln][c];
        float4 s1 = *(const float4*)&red[1][ln][c];
        float4 s2 = *(const float4*)&red[2][ln][c];
        float4 s3 = *(const float4*)&red[3][ln][c];
        float4 bv = *(const float4*)(b5 + c);
        *(float4*)&g3f[ln][c] = make_float4(
            fmaxf(s0.x + s1.x + s2.x + s3.x + bv.x, 0.f),
            fmaxf(s0.y + s1.y + s2.y + s3.y + bv.y, 0.f),
            fmaxf(s0.z + s1.z + s2.z + s3.z + bv.z, 0.f),
            fmaxf(s0.w + s1.w + s2.w + s3.w + bv.w, 0.f));
    }
    __syncthreads();

    // ---- fc: 16 nodes x 40 outputs ----
    for (int idx = tid; idx < NPB * 40; idx += 256) {
        int ln = idx / 40;
        int c = idx - ln * 40;
        float o = bf[c];
#pragma unroll 4
        for (int j = 0; j < 64; ++j)
            o = fmaf(g3f[ln][j], Wf[j * 40 + c], o);
        os[ln][c] = o;
    }
    __syncthreads();

    // ---- log_softmax + store ----
    if (tid < NPB) {
        int ln = tid;
        if (n0 + ln < N) {
            float mx = os[ln][0];
#pragma unroll
            for (int c = 1; c < 40; ++c) mx = fmaxf(mx, os[ln][c]);
            float s = 0.f;
#pragma unroll
            for (int c = 0; c < 40; ++c) s += expf(os[ln][c] - mx);
            float ls = logf(s) + mx;
            float* op = out + (size_t)(n0 + ln) * 40;
#pragma unroll
            for (int c = 0; c < 40; ++c) op[c] = os[ln][c] - ls;
        }
    }
}

// ============================ launch ============================
extern "C" void kernel_launch(void* const* d_in, const int* in_sizes, int n_in,
                              void* d_out, int out_size, void* d_ws, size_t ws_size,
                              hipStream_t stream) {
    const float* x   = (const float*)d_in[0];
    const float* pos = (const float*)d_in[1];
    const int*   ei  = (const int*)d_in[2];
    const float* W1  = (const float*)d_in[3];
    const float* b1  = (const float*)d_in[4];
    const float* W2  = (const float*)d_in[5];
    const float* b2  = (const float*)d_in[6];
    const float* W3  = (const float*)d_in[7];
    const float* b3  = (const float*)d_in[8];
    const float* W4  = (const float*)d_in[9];
    const float* b4  = (const float*)d_in[10];
    const float* W5  = (const float*)d_in[11];
    const float* b5  = (const float*)d_in[12];
    const float* Wf  = (const float*)d_in[13];
    const float* bf  = (const float*)d_in[14];
    float* out = (float*)d_out;

    int Nn = in_sizes[0] / 3;   // 50000
    int E  = in_sizes[2] / 2;   // 1600000

    char* w = (char*)d_ws;
    size_t p = 0;
    auto take = [&](size_t bytes) { size_t q = p; p = (p + bytes + 255) & ~size_t(255); return (void*)(w + q); };
    unsigned int* off  = (unsigned int*)take((size_t)Nn * 4);
    unsigned int* cnt  = (unsigned int*)take((size_t)Nn * 4);   // reused as cursor
    unsigned int* list = (unsigned int*)take((size_t)(E + Nn) * 4);
    float*        agg  = (float*)take((size_t)Nn * 64 * 4);

    k_init_cnt<<<(Nn + 255) / 256, 256, 0, stream>>>(cnt, Nn);
    k_count<<<(E + 255) / 256, 256, 0, stream>>>(ei, E, cnt);
    k_scan<<<1, 1024, 0, stream>>>(cnt, off, Nn);
    k_fill<<<(Nn + 255) / 256, 256, 0, stream>>>(off, cnt, list, Nn);
    k_scatter<<<(E + 255) / 256, 256, 0, stream>>>(ei, E, cnt, list);

    int totalWaves = (Nn + 3) / 4;                       // ~4 dsts per wave
    int eBlocks = (totalWaves + EDGE_WPB - 1) / EDGE_WPB;
    int dstStride = eBlocks * EDGE_WPB;
    edge_kernel<<<eBlocks, TPB_E, 0, stream>>>(
        x, pos, off, cnt, list, W1, b1, W2, b2, agg, Nn, dstStride);

    node_kernel<<<(Nn + NPB - 1) / NPB, 256, 0, stream>>>(
        agg, W3, b3, W4, b4, W5, b5, Wf, bf, out, Nn);
}

// Round 5
// 1377.736 us; speedup vs baseline: 2.9555x; 2.0453x over previous
//
#include <hip/hip_runtime.h>
#include <cstddef>
#include <cmath>

// ============================ CSR build ============================
__global__ void k_init_cnt(unsigned int* __restrict__ cnt, int N) {
    int i = blockIdx.x * 256 + threadIdx.x;
    if (i < N) cnt[i] = 1u;   // self-loop pre-counted
}

__global__ void k_count(const int* __restrict__ ei, int E, unsigned int* __restrict__ cnt) {
    int e = blockIdx.x * 256 + threadIdx.x;
    if (e < E) atomicAdd(&cnt[ei[E + e]], 1u);
}

__global__ __launch_bounds__(1024) void k_scan(const unsigned int* __restrict__ cnt,
                                               unsigned int* __restrict__ off, int N) {
    __shared__ unsigned int sums[1024];
    int t = threadIdx.x;
    int chunk = (N + 1023) >> 10;
    int lo = t * chunk, hi = min(lo + chunk, N);
    unsigned int s = 0;
    for (int i = lo; i < hi; ++i) s += cnt[i];
    sums[t] = s;
    __syncthreads();
    for (int d = 1; d < 1024; d <<= 1) {
        unsigned int v = (t >= d) ? sums[t - d] : 0u;
        __syncthreads();
        sums[t] += v;
        __syncthreads();
    }
    unsigned int run = (t == 0) ? 0u : sums[t - 1];
    for (int i = lo; i < hi; ++i) { off[i] = run; run += cnt[i]; }
}

__global__ void k_fill(const unsigned int* __restrict__ off, unsigned int* __restrict__ cur,
                       unsigned int* __restrict__ list, int N) {
    int n = blockIdx.x * 256 + threadIdx.x;
    if (n < N) { unsigned int o = off[n]; list[o] = (unsigned int)n; cur[n] = o + 1u; }
}

__global__ void k_scatter(const int* __restrict__ ei, int E,
                          unsigned int* __restrict__ cur, unsigned int* __restrict__ list) {
    int e = blockIdx.x * 256 + threadIdx.x;
    if (e < E) {
        int d = ei[E + e];
        unsigned int p = atomicAdd(&cur[d], 1u);
        list[p] = (unsigned int)ei[e];
    }
}

// ===================== edge kernel: one wave per dst (unchanged from R4) =====================
static __device__ __forceinline__ float rl(float v, int l) {
    return __int_as_float(__builtin_amdgcn_readlane(__float_as_int(v), l));
}

#define TPB_E 256
#define EDGE_WPB 4
__global__ __launch_bounds__(TPB_E, 3) void edge_kernel(
    const float* __restrict__ x, const float* __restrict__ pos,
    const unsigned int* __restrict__ off, const unsigned int* __restrict__ cur,
    const unsigned int* __restrict__ list,
    const float* __restrict__ W1, const float* __restrict__ b1,
    const float* __restrict__ W2, const float* __restrict__ b2,
    float* __restrict__ agg, int N, int dstStride)
{
    int lane = threadIdx.x & 63;
    int dst0 = blockIdx.x * EDGE_WPB + (threadIdx.x >> 6);

    float w1c[6];
#pragma unroll
    for (int k = 0; k < 6; ++k) w1c[k] = W1[k * 64 + lane];
    float b1c = b1[lane], b2c = b2[lane];
    float w2c[64];
#pragma unroll
    for (int j = 0; j < 64; ++j) w2c[j] = W2[j * 64 + lane];
#pragma unroll
    for (int k = 0; k < 6; ++k) asm volatile("" : "+v"(w1c[k]));
#pragma unroll
    for (int j = 0; j < 64; ++j) asm volatile("" : "+v"(w2c[j]));

    for (int dst = dst0; dst < N; dst += dstStride) {
        unsigned int o0 = off[dst];
        int cnt = (int)(cur[dst] - o0);
        float pi0 = pos[dst * 3 + 0], pi1 = pos[dst * 3 + 1], pi2 = pos[dst * 3 + 2];
        float m = -INFINITY;

        float in0 = 0.f, in1 = 0.f, in2 = 0.f, in3 = 0.f, in4 = 0.f, in5 = 0.f;
        if (lane < 8) {
            int i = lane;
            int s = (i < cnt) ? (int)list[o0 + i] : dst;
            in0 = x[s * 3 + 0]; in1 = x[s * 3 + 1]; in2 = x[s * 3 + 2];
            in3 = pos[s * 3 + 0] - pi0; in4 = pos[s * 3 + 1] - pi1; in5 = pos[s * 3 + 2] - pi2;
        }

        for (int base = 0; base < cnt; base += 8) {
            int nb = min(8, cnt - base);
            float n0 = 0.f, n1 = 0.f, n2 = 0.f, n3 = 0.f, n4 = 0.f, n5 = 0.f;
            if (lane < 8 && base + 8 < cnt) {
                int i = base + 8 + lane;
                int s = (i < cnt) ? (int)list[o0 + i] : dst;
                n0 = x[s * 3 + 0]; n1 = x[s * 3 + 1]; n2 = x[s * 3 + 2];
                n3 = pos[s * 3 + 0] - pi0; n4 = pos[s * 3 + 1] - pi1; n5 = pos[s * 3 + 2] - pi2;
            }
            float h[8];
#pragma unroll
            for (int e = 0; e < 8; ++e) {
                float t = b1c;
                t = fmaf(rl(in0, e), w1c[0], t);
                t = fmaf(rl(in1, e), w1c[1], t);
                t = fmaf(rl(in2, e), w1c[2], t);
                t = fmaf(rl(in3, e), w1c[3], t);
                t = fmaf(rl(in4, e), w1c[4], t);
                t = fmaf(rl(in5, e), w1c[5], t);
                h[e] = fmaxf(t, 0.f);
            }
#pragma unroll
            for (int e = 0; e < 8; ++e) {
                if (e >= nb) break;
                int hh = __float_as_int(h[e]);
                float t0 = b2c, t1 = 0.f, t2 = 0.f, t3 = 0.f;
#pragma unroll
                for (int j = 0; j < 64; j += 4) {
                    t0 = fmaf(__int_as_float(__builtin_amdgcn_readlane(hh, j + 0)), w2c[j + 0], t0);
                    t1 = fmaf(__int_as_float(__builtin_amdgcn_readlane(hh, j + 1)), w2c[j + 1], t1);
                    t2 = fmaf(__int_as_float(__builtin_amdgcn_readlane(hh, j + 2)), w2c[j + 2], t2);
                    t3 = fmaf(__int_as_float(__builtin_amdgcn_readlane(hh, j + 3)), w2c[j + 3], t3);
                }
                m = fmaxf(m, (t0 + t1) + (t2 + t3));
            }
            in0 = n0; in1 = n1; in2 = n2; in3 = n3; in4 = n4; in5 = n5;
        }
        agg[(size_t)dst * 64 + lane] = m;
    }
}

// ===================== node kernel: fused GEMM chain, 32 nodes/block =====================
// All per-thread accumulator tiles are <=16 floats (R1-R4 lesson: this compiler
// spills any 64-float array regardless of launch_bounds). Thread tile: 2 nodes x
// 4 cols. Activations round-trip via node-major padded LDS (broadcast reads).
#define NODES 32
__global__ __launch_bounds__(256, 3) void node_kernel(
    const float* __restrict__ agg,
    const float* __restrict__ W3, const float* __restrict__ b3,
    const float* __restrict__ W4, const float* __restrict__ b4,
    const float* __restrict__ W5, const float* __restrict__ b5,
    const float* __restrict__ Wf, const float* __restrict__ bf,
    float* __restrict__ out, int N)
{
    __shared__ float regionA[NODES * 68];       // As[32][68] then G3s[32][68]
    __shared__ float G1s[NODES][132];           // g1, node-major
    __shared__ float G2s[2][NODES][68];         // g2 chunk, double-buffered
    __shared__ float os[NODES][41];             // fc outputs

    float (*As)[68]  = (float(*)[68])regionA;
    float (*G3s)[68] = (float(*)[68])regionA;

    int tid = threadIdx.x;
    int n0 = blockIdx.x * NODES;

    // ---- stage agg tile (coalesced float4, clamped) ----
    {
        int v = tid;                       // float4 index 0..511
        int node = v >> 4, kpos = (v & 15) * 4;
        int src = min(n0 + node, N - 1);
        float4 a = *(const float4*)(agg + (size_t)src * 64 + kpos);
        *(float4*)&As[node][kpos] = a;
        v = tid + 256;
        node = v >> 4; kpos = (v & 15) * 4;
        src = min(n0 + node, N - 1);
        a = *(const float4*)(agg + (size_t)src * 64 + kpos);
        *(float4*)&As[node][kpos] = a;
    }
    __syncthreads();

    // ---- L3: g1[32][128] = relu(agg @ W3 + b3). thread: 4 nodes x 4 cols ----
    {
        int cg = tid & 31;         // col group: col = cg*4, covers 128
        int q  = tid >> 5;         // node quad: nodes q*4..q*4+3
        int col = cg * 4;
        float acc[4][4];
#pragma unroll
        for (int j = 0; j < 4; ++j) {
            float4 bv = *(const float4*)(b3 + col);
            acc[j][0] = bv.x; acc[j][1] = bv.y; acc[j][2] = bv.z; acc[j][3] = bv.w;
        }
        for (int k = 0; k < 64; ++k) {
            float4 wv = *(const float4*)(W3 + k * 128 + col);
            float a0 = As[q * 4 + 0][k], a1 = As[q * 4 + 1][k];
            float a2 = As[q * 4 + 2][k], a3 = As[q * 4 + 3][k];
            acc[0][0] = fmaf(a0, wv.x, acc[0][0]); acc[0][1] = fmaf(a0, wv.y, acc[0][1]);
            acc[0][2] = fmaf(a0, wv.z, acc[0][2]); acc[0][3] = fmaf(a0, wv.w, acc[0][3]);
            acc[1][0] = fmaf(a1, wv.x, acc[1][0]); acc[1][1] = fmaf(a1, wv.y, acc[1][1]);
            acc[1][2] = fmaf(a1, wv.z, acc[1][2]); acc[1][3] = fmaf(a1, wv.w, acc[1][3]);
            acc[2][0] = fmaf(a2, wv.x, acc[2][0]); acc[2][1] = fmaf(a2, wv.y, acc[2][1]);
            acc[2][2] = fmaf(a2, wv.z, acc[2][2]); acc[2][3] = fmaf(a2, wv.w, acc[2][3]);
            acc[3][0] = fmaf(a3, wv.x, acc[3][0]); acc[3][1] = fmaf(a3, wv.y, acc[3][1]);
            acc[3][2] = fmaf(a3, wv.z, acc[3][2]); acc[3][3] = fmaf(a3, wv.w, acc[3][3]);
        }
#pragma unroll
        for (int j = 0; j < 4; ++j) {
            *(float4*)&G1s[q * 4 + j][col] = make_float4(
                fmaxf(acc[j][0], 0.f), fmaxf(acc[j][1], 0.f),
                fmaxf(acc[j][2], 0.f), fmaxf(acc[j][3], 0.f));
        }
    }
    __syncthreads();

    // ---- L4+L5 fused over 16 chunks of 64 g2-channels ----
    int cg = tid & 15;          // col group: 4 cols
    int np = tid >> 4;          // node pair: nodes np*2, np*2+1
    int col = cg * 4;
    int nA = np * 2, nB = np * 2 + 1;

    float g3[2][4];             // final-layer accumulator: 2 nodes x 4 outs
    {
        float4 bv = *(const float4*)(b5 + col);
        g3[0][0] = bv.x; g3[0][1] = bv.y; g3[0][2] = bv.z; g3[0][3] = bv.w;
        g3[1][0] = bv.x; g3[1][1] = bv.y; g3[1][2] = bv.z; g3[1][3] = bv.w;
    }

    for (int ch = 0; ch < 16; ++ch) {
        int buf = ch & 1;
        // L4: g2 chunk cols [ch*64+col .. +4) for 2 nodes
        float t[2][4];
        {
            float4 bv = *(const float4*)(b4 + ch * 64 + col);
            t[0][0] = bv.x; t[0][1] = bv.y; t[0][2] = bv.z; t[0][3] = bv.w;
            t[1][0] = bv.x; t[1][1] = bv.y; t[1][2] = bv.z; t[1][3] = bv.w;
        }
        for (int k = 0; k < 128; ++k) {
            float4 wv = *(const float4*)(W4 + (size_t)k * 1024 + ch * 64 + col);
            float gA = G1s[nA][k], gB = G1s[nB][k];
            t[0][0] = fmaf(gA, wv.x, t[0][0]); t[0][1] = fmaf(gA, wv.y, t[0][1]);
            t[0][2] = fmaf(gA, wv.z, t[0][2]); t[0][3] = fmaf(gA, wv.w, t[0][3]);
            t[1][0] = fmaf(gB, wv.x, t[1][0]); t[1][1] = fmaf(gB, wv.y, t[1][1]);
            t[1][2] = fmaf(gB, wv.z, t[1][2]); t[1][3] = fmaf(gB, wv.w, t[1][3]);
        }
        *(float4*)&G2s[buf][nA][col] = make_float4(
            fmaxf(t[0][0], 0.f), fmaxf(t[0][1], 0.f), fmaxf(t[0][2], 0.f), fmaxf(t[0][3], 0.f));
        *(float4*)&G2s[buf][nB][col] = make_float4(
            fmaxf(t[1][0], 0.f), fmaxf(t[1][1], 0.f), fmaxf(t[1][2], 0.f), fmaxf(t[1][3], 0.f));
        __syncthreads();
        // L5: accumulate g2chunk @ W5[ch*64 .. +64)
        for (int k = 0; k < 64; ++k) {
            float4 wv = *(const float4*)(W5 + (size_t)(ch * 64 + k) * 64 + col);
            float gA = G2s[buf][nA][k], gB = G2s[buf][nB][k];
            g3[0][0] = fmaf(gA, wv.x, g3[0][0]); g3[0][1] = fmaf(gA, wv.y, g3[0][1]);
            g3[0][2] = fmaf(gA, wv.z, g3[0][2]); g3[0][3] = fmaf(gA, wv.w, g3[0][3]);
            g3[1][0] = fmaf(gB, wv.x, g3[1][0]); g3[1][1] = fmaf(gB, wv.y, g3[1][1]);
            g3[1][2] = fmaf(gB, wv.z, g3[1][2]); g3[1][3] = fmaf(gB, wv.w, g3[1][3]);
        }
    }
    __syncthreads();   // all G2s reads done; regionA reuse is safe (As long dead)

    // ---- stage relu(g3) ----
    *(float4*)&G3s[nA][col] = make_float4(
        fmaxf(g3[0][0], 0.f), fmaxf(g3[0][1], 0.f), fmaxf(g3[0][2], 0.f), fmaxf(g3[0][3], 0.f));
    *(float4*)&G3s[nB][col] = make_float4(
        fmaxf(g3[1][0], 0.f), fmaxf(g3[1][1], 0.f), fmaxf(g3[1][2], 0.f), fmaxf(g3[1][3], 0.f));
    __syncthreads();

    // ---- fc: 32 nodes x 40 outputs ----
    for (int idx = tid; idx < NODES * 40; idx += 256) {
        int ln = idx / 40;
        int c = idx - ln * 40;
        float o = bf[c];
#pragma unroll 4
        for (int j = 0; j < 64; ++j)
            o = fmaf(G3s[ln][j], Wf[j * 40 + c], o);
        os[ln][c] = o;
    }
    __syncthreads();

    // ---- log_softmax + store ----
    if (tid < NODES && n0 + tid < N) {
        int ln = tid;
        float mx = os[ln][0];
#pragma unroll
        for (int c = 1; c < 40; ++c) mx = fmaxf(mx, os[ln][c]);
        float s = 0.f;
#pragma unroll
        for (int c = 0; c < 40; ++c) s += expf(os[ln][c] - mx);
        float ls = logf(s) + mx;
        float* op = out + (size_t)(n0 + ln) * 40;
#pragma unroll
        for (int c = 0; c < 40; ++c) op[c] = os[ln][c] - ls;
    }
}

// ============================ launch ============================
extern "C" void kernel_launch(void* const* d_in, const int* in_sizes, int n_in,
                              void* d_out, int out_size, void* d_ws, size_t ws_size,
                              hipStream_t stream) {
    const float* x   = (const float*)d_in[0];
    const float* pos = (const float*)d_in[1];
    const int*   ei  = (const int*)d_in[2];
    const float* W1  = (const float*)d_in[3];
    const float* b1  = (const float*)d_in[4];
    const float* W2  = (const float*)d_in[5];
    const float* b2  = (const float*)d_in[6];
    const float* W3  = (const float*)d_in[7];
    const float* b3  = (const float*)d_in[8];
    const float* W4  = (const float*)d_in[9];
    const float* b4  = (const float*)d_in[10];
    const float* W5  = (const float*)d_in[11];
    const float* b5  = (const float*)d_in[12];
    const float* Wf  = (const float*)d_in[13];
    const float* bf  = (const float*)d_in[14];
    float* out = (float*)d_out;

    int Nn = in_sizes[0] / 3;   // 50000
    int E  = in_sizes[2] / 2;   // 1600000

    char* w = (char*)d_ws;
    size_t p = 0;
    auto take = [&](size_t bytes) { size_t q = p; p = (p + bytes + 255) & ~size_t(255); return (void*)(w + q); };
    unsigned int* off  = (unsigned int*)take((size_t)Nn * 4);
    unsigned int* cnt  = (unsigned int*)take((size_t)Nn * 4);   // reused as cursor
    unsigned int* list = (unsigned int*)take((size_t)(E + Nn) * 4);
    float*        agg  = (float*)take((size_t)Nn * 64 * 4);

    k_init_cnt<<<(Nn + 255) / 256, 256, 0, stream>>>(cnt, Nn);
    k_count<<<(E + 255) / 256, 256, 0, stream>>>(ei, E, cnt);
    k_scan<<<1, 1024, 0, stream>>>(cnt, off, Nn);
    k_fill<<<(Nn + 255) / 256, 256, 0, stream>>>(off, cnt, list, Nn);
    k_scatter<<<(E + 255) / 256, 256, 0, stream>>>(ei, E, cnt, list);

    int totalWaves = (Nn + 3) / 4;
    int eBlocks = (totalWaves + EDGE_WPB - 1) / EDGE_WPB;
    int dstStride = eBlocks * EDGE_WPB;
    edge_kernel<<<eBlocks, TPB_E, 0, stream>>>(
        x, pos, off, cnt, list, W1, b1, W2, b2, agg, Nn, dstStride);

    node_kernel<<<(Nn + NODES - 1) / NODES, 256, 0, stream>>>(
        agg, W3, b3, W4, b4, W5, b5, Wf, bf, out, Nn);
}